// Round 1
// baseline (13431.042 us; speedup 1.0000x reference)
//
#include <hip/hip_runtime.h>
#include <hip/hip_bf16.h>

#define BB 32
#define SS 128
#define CC 128
#define HH 128
#define OO 64
// gates = 3*HH = 384

__device__ __forceinline__ float sigmoidf_(float x) {
    return 1.0f / (1.0f + __expf(-x));
}
__device__ __forceinline__ float tanh_fast_(float x) {
    // tanh(x) = 1 - 2/(exp(2x)+1); exp range here is safe (|x| <= ~16)
    return 1.0f - 2.0f / (__expf(2.0f * x) + 1.0f);
}

// One workgroup per (direction, batch): runs the full 16384-step chain.
// Thread t in [0,384) owns gate row t. Whh row lives in VGPRs (32 x float4).
// h double-buffered in LDS; x[b] slice staged in LDS (64KB).
__global__ __launch_bounds__(384, 1) void gru_chain_kernel(
    const float* __restrict__ x,       // (B,S,C)
    const float* __restrict__ h_prev,  // (2,B,H)
    const float* __restrict__ Wih_f, const float* __restrict__ Whh_f,
    const float* __restrict__ bih_f, const float* __restrict__ bhh_f,
    const float* __restrict__ Wih_b, const float* __restrict__ Whh_b,
    const float* __restrict__ bih_b, const float* __restrict__ bhh_b,
    float* __restrict__ hsnap)         // (2, C, B, H) column-end snapshots
{
    const int wg = blockIdx.x;
    const int d  = wg >> 5;        // 0 = forward, 1 = backward
    const int b  = wg & 31;
    const int t  = threadIdx.x;    // 0..383

    const float* __restrict__ Wih = d ? Wih_b : Wih_f;
    const float* __restrict__ Whh = d ? Whh_b : Whh_f;
    const float* __restrict__ bih = d ? bih_b : bih_f;
    const float* __restrict__ bhh = d ? bhh_b : bhh_f;

    __shared__ float xs[SS * CC];      // 64KB, layout [t][c] (same as input slice)
    __shared__ float hbuf[2][HH];      // double-buffered hidden state
    __shared__ float gate[2 * HH];     // r in [0,H), z in [H,2H)

    // stage x[b] (contiguous 16384 floats) into LDS, coalesced float4
    {
        const float4* xb4 = reinterpret_cast<const float4*>(x + (size_t)b * SS * CC);
        float4* xs4 = reinterpret_cast<float4*>(xs);
        for (int i = t; i < SS * CC / 4; i += 384) xs4[i] = xb4[i];
    }

    // per-thread weight row -> 32 float4 in VGPRs
    float4 w[32];
    {
        const float4* wr = reinterpret_cast<const float4*>(Whh + t * HH);
        #pragma unroll
        for (int k = 0; k < 32; ++k) w[k] = wr[k];
    }
    const float wih_t = Wih[t];
    const float bih_t = bih[t];
    const float bhh_t = bhh[t];

    if (t < HH) hbuf[0][t] = h_prev[(d * BB + b) * HH + t];
    __syncthreads();

    int p = 0;
    for (int s = 0; s < SS * CC; ++s) {
        const int c  = s >> 7;                   // column index
        const int ts = s & (SS - 1);             // step within column
        const int tt = d ? (SS - 1 - ts) : ts;   // backward reads reversed rows
        const float xv = xs[tt * CC + c];        // broadcast LDS read

        // gh[t] = dot(Whh[t,:], h) ; 4 accumulators to pipeline the FMA chain
        float a0 = 0.f, a1 = 0.f, a2 = 0.f, a3 = 0.f;
        const float4* h4 = reinterpret_cast<const float4*>(hbuf[p]);
        #pragma unroll
        for (int k = 0; k < 32; ++k) {
            const float4 hv = h4[k];             // broadcast (same addr all lanes)
            a0 = fmaf(w[k].x, hv.x, a0);
            a1 = fmaf(w[k].y, hv.y, a1);
            a2 = fmaf(w[k].z, hv.z, a2);
            a3 = fmaf(w[k].w, hv.w, a3);
        }
        const float gh = (a0 + a1) + (a2 + a3) + bhh_t;
        const float gi = fmaf(xv, wih_t, bih_t);

        if (t < 2 * HH) gate[t] = sigmoidf_(gi + gh);   // r and z gates
        __syncthreads();                                 // barrier A: r,z ready
        if (t >= 2 * HH) {
            const int j = t - 2 * HH;
            const float r  = gate[j];
            const float z  = gate[HH + j];
            const float n  = tanh_fast_(fmaf(r, gh, gi)); // tanh(inn + r*hn)
            const float hp = hbuf[p][j];
            const float hn = fmaf(z, hp - n, n);          // (1-z)*n + z*h
            hbuf[p ^ 1][j] = hn;
            if (ts == SS - 1) {
                hsnap[(((size_t)d * CC + c) * BB + b) * HH + j] = hn;
            }
        }
        __syncthreads();                                 // barrier B: h' ready
        p ^= 1;
    }
}

// One block (= one wave of 64 threads) per (c,b): FC + ReLU + softmax over O=64.
__global__ __launch_bounds__(64) void fc_softmax_kernel(
    const float* __restrict__ hsnap,   // (2, C, B, H)
    const float* __restrict__ W_fc,    // (O, 2H)
    const float* __restrict__ b_fc,    // (O,)
    float* __restrict__ out)           // (B, C, O)
{
    const int cb = blockIdx.x;         // c * B + b
    const int c  = cb >> 5;
    const int b  = cb & 31;
    const int o  = threadIdx.x;        // 0..63

    __shared__ float feat[2 * HH];     // [hf, hb]
    #pragma unroll
    for (int i = 0; i < 4; ++i) {
        const int idx = i * 64 + o;            // 0..255
        const int dd  = idx >> 7;              // 0: hf, 1: hb
        const int j   = idx & (HH - 1);
        feat[idx] = hsnap[(((size_t)dd * CC + c) * BB + b) * HH + j];
    }
    __syncthreads();

    float acc = 0.f;
    const float4* wrow = reinterpret_cast<const float4*>(W_fc + o * 2 * HH);
    const float4* f4   = reinterpret_cast<const float4*>(feat);
    #pragma unroll
    for (int k = 0; k < 64; ++k) {
        const float4 wv = wrow[k];
        const float4 fv = f4[k];
        acc = fmaf(wv.x, fv.x, acc);
        acc = fmaf(wv.y, fv.y, acc);
        acc = fmaf(wv.z, fv.z, acc);
        acc = fmaf(wv.w, fv.w, acc);
    }
    float v = fmaxf(acc + b_fc[o], 0.0f);

    // softmax across the 64-lane wave
    float m = v;
    #pragma unroll
    for (int off = 32; off; off >>= 1) m = fmaxf(m, __shfl_xor(m, off));
    const float e = __expf(v - m);
    float ssum = e;
    #pragma unroll
    for (int off = 32; off; off >>= 1) ssum += __shfl_xor(ssum, off);

    out[((size_t)b * CC + c) * OO + o] = e / ssum;
}

extern "C" void kernel_launch(void* const* d_in, const int* in_sizes, int n_in,
                              void* d_out, int out_size, void* d_ws, size_t ws_size,
                              hipStream_t stream) {
    const float* x      = (const float*)d_in[0];
    const float* h_prev = (const float*)d_in[1];
    const float* Wih_f  = (const float*)d_in[2];
    const float* Whh_f  = (const float*)d_in[3];
    const float* bih_f  = (const float*)d_in[4];
    const float* bhh_f  = (const float*)d_in[5];
    const float* Wih_b  = (const float*)d_in[6];
    const float* Whh_b  = (const float*)d_in[7];
    const float* bih_b  = (const float*)d_in[8];
    const float* bhh_b  = (const float*)d_in[9];
    const float* W_fc   = (const float*)d_in[10];
    const float* b_fc   = (const float*)d_in[11];
    float* out   = (float*)d_out;
    float* hsnap = (float*)d_ws;   // needs 2*C*B*H*4 = 4 MiB of scratch

    gru_chain_kernel<<<64, 384, 0, stream>>>(x, h_prev, Wih_f, Whh_f, bih_f, bhh_f,
                                             Wih_b, Whh_b, bih_b, bhh_b, hsnap);
    fc_softmax_kernel<<<CC * BB, 64, 0, stream>>>(hsnap, W_fc, b_fc, out);
}